// Round 2
// baseline (6616.505 us; speedup 1.0000x reference)
//
#include <hip/hip_runtime.h>
#include <hip/hip_bf16.h>

// Decoder: attention + LSTMCell + proj + vocab scoring.
// B=32, S=512, T=64, DENC=DHID=1024, DEMB=512, V=32000.
// Precision plan: recurrent state f32; all GEMMs use split-bf16 (hi/lo)
// inputs so they are effectively f32-accurate. Vocab GEMM hoisted out of
// the T-loop; P split hi/lo, emb single bf16.

#define B_   32
#define S_   512
#define T_   64
#define DENC 1024
#define DHID 1024
#define DEMB 512
#define V_   32000
#define KX   2560   // X row: [ctx 1024 | h 1024 | e 512]
#define KP   2048   // proj K: [ctx | h]

using short8 = __attribute__((ext_vector_type(8))) short;
using f32x4  = __attribute__((ext_vector_type(4))) float;
typedef __hip_bfloat16 bf16;

__device__ __forceinline__ float sigmoidf_(float x) { return 1.0f / (1.0f + expf(-x)); }
__device__ __forceinline__ bf16 bhi(float x) { return __float2bfloat16(x); }
__device__ __forceinline__ bf16 blo(float x) {
    return __float2bfloat16(x - __bfloat162float(__float2bfloat16(x)));
}

// ---------------- setup kernels ----------------

// Wg rows reordered j' = d*4 + gate so LSTM pointwise fuses into gates epilogue.
__global__ void k_build_wg(const float* __restrict__ W_ih, const float* __restrict__ W_hh,
                           const float* __restrict__ b_ih, const float* __restrict__ b_hh,
                           bf16* __restrict__ Wh, bf16* __restrict__ Wl, float* __restrict__ bias) {
    int jp = blockIdx.x;            // 0..4095
    int g = jp & 3, d = jp >> 2;
    int j = g * 1024 + d;           // source row (torch gate order i,f,g,o)
    const float* wi = W_ih + (size_t)j * 1536;
    const float* wh = W_hh + (size_t)j * 1024;
    bf16* dh = Wh + (size_t)jp * KX;
    bf16* dl = Wl + (size_t)jp * KX;
    for (int i = threadIdx.x; i < 1024; i += 256) { float v = wi[i];        dh[i] = bhi(v);        dl[i] = blo(v); }
    for (int i = threadIdx.x; i < 1024; i += 256) { float v = wh[i];        dh[1024+i] = bhi(v);   dl[1024+i] = blo(v); }
    for (int i = threadIdx.x; i < 512;  i += 256) { float v = wi[1024+i];   dh[2048+i] = bhi(v);   dl[2048+i] = blo(v); }
    if (threadIdx.x == 0) bias[jp] = b_ih[j] + b_hh[j];
}

__global__ void k_cvt(const float* __restrict__ src, bf16* __restrict__ dst, long n) {
    long i = (long)blockIdx.x * blockDim.x + threadIdx.x;
    long stride = (long)gridDim.x * blockDim.x;
    for (; i < n; i += stride) dst[i] = __float2bfloat16(src[i]);
}

__global__ void k_cvt_split(const float* __restrict__ src, bf16* __restrict__ dh,
                            bf16* __restrict__ dl, long n) {
    long i = (long)blockIdx.x * blockDim.x + threadIdx.x;
    long stride = (long)gridDim.x * blockDim.x;
    for (; i < n; i += stride) { float v = src[i]; dh[i] = bhi(v); dl[i] = blo(v); }
}

__global__ void k_init(const float* __restrict__ h0, const float* __restrict__ c0,
                       const float* __restrict__ emb0,
                       float* __restrict__ h, float* __restrict__ c,
                       bf16* __restrict__ Xh_, bf16* __restrict__ Xl_,
                       bf16* __restrict__ Hh, bf16* __restrict__ Hl) {
    int b = blockIdx.x;   // 32 blocks
    for (int d = threadIdx.x; d < 1024; d += 256) {
        float v = h0[d];
        h[b * 1024 + d] = v;
        c[b * 1024 + d] = c0[d];
        Hh[b * 1024 + d] = bhi(v);
        Hl[b * 1024 + d] = blo(v);
        Xh_[(size_t)b * KX + 1024 + d] = bhi(v);
        Xl_[(size_t)b * KX + 1024 + d] = blo(v);
    }
    for (int d = threadIdx.x; d < 512; d += 256) {
        float v = emb0[d];
        Xh_[(size_t)b * KX + 2048 + d] = bhi(v);
        Xl_[(size_t)b * KX + 2048 + d] = blo(v);
    }
}

// ---------------- per-step kernels ----------------

// score[b][s] = dot(enc[b][s], h[b]) - (1-mask)*1e20.   grid (32,8), 256 thr
__global__ __launch_bounds__(256) void k_score(const float* __restrict__ enc,
                                               const float* __restrict__ mask,
                                               const float* __restrict__ h,
                                               float* __restrict__ score) {
    int b = blockIdx.x, sc = blockIdx.y;
    __shared__ float hs[1024];
    int tid = threadIdx.x;
    ((float4*)hs)[tid] = ((const float4*)(h + b * 1024))[tid];
    __syncthreads();
    int wave = tid >> 6, lane = tid & 63;
    const float* encb = enc + (size_t)b * S_ * DENC;
    const float4* hs4 = (const float4*)hs;
    for (int i = 0; i < 16; ++i) {
        int s = sc * 64 + wave * 16 + i;
        const float4* row = (const float4*)(encb + (size_t)s * DENC);
        float acc = 0.f;
#pragma unroll
        for (int r = 0; r < 4; ++r) {
            float4 e4 = row[r * 64 + lane];
            float4 h4 = hs4[r * 64 + lane];
            acc = fmaf(e4.x, h4.x, acc); acc = fmaf(e4.y, h4.y, acc);
            acc = fmaf(e4.z, h4.z, acc); acc = fmaf(e4.w, h4.w, acc);
        }
#pragma unroll
        for (int off = 32; off; off >>= 1) acc += __shfl_xor(acc, off, 64);
        if (lane == 0) score[b * S_ + s] = acc - (1.0f - mask[b * S_ + s]) * 1e20f;
    }
}

// softmax (recomputed per block, f32) + ctx accumulation (f32) -> X ctx part (split bf16).
// Also copies Hh/Hl (h_{t-1}) into X h-part. grid (32,8), 256 thr.
__global__ __launch_bounds__(256) void k_ctx(const float* __restrict__ enc,
                                             const float* __restrict__ score,
                                             const bf16* __restrict__ Hh,
                                             const bf16* __restrict__ Hl,
                                             bf16* __restrict__ Xh_, bf16* __restrict__ Xl_) {
    int b = blockIdx.x, dc = blockIdx.y;
    int tid = threadIdx.x;
    int wave = tid >> 6, lane = tid & 63;
    __shared__ float attn[512];
    __shared__ float red[8];
    __shared__ float part[256];

    float s0 = score[b * 512 + tid], s1 = score[b * 512 + 256 + tid];
    float m = fmaxf(s0, s1);
#pragma unroll
    for (int off = 32; off; off >>= 1) m = fmaxf(m, __shfl_xor(m, off, 64));
    if (lane == 0) red[wave] = m;
    __syncthreads();
    m = fmaxf(fmaxf(red[0], red[1]), fmaxf(red[2], red[3]));
    float e0 = expf(s0 - m), e1 = expf(s1 - m);
    float sum = e0 + e1;
#pragma unroll
    for (int off = 32; off; off >>= 1) sum += __shfl_xor(sum, off, 64);
    if (lane == 0) red[4 + wave] = sum;
    __syncthreads();
    float inv = 1.0f / (red[4] + red[5] + red[6] + red[7]);
    attn[tid] = e0 * inv;
    attn[256 + tid] = e1 * inv;
    __syncthreads();

    int d = dc * 128 + (tid & 127);
    int sh = tid >> 7;
    const float* ep = enc + (size_t)b * S_ * DENC + d;
    float acc = 0.f;
    int sbeg = sh * 256;
#pragma unroll 8
    for (int s = sbeg; s < sbeg + 256; ++s) acc = fmaf(attn[s], ep[(size_t)s * DENC], acc);
    part[tid] = acc;
    __syncthreads();
    if (tid < 128) {
        float v = part[tid] + part[tid + 128];
        Xh_[(size_t)b * KX + d] = bhi(v);
        Xl_[(size_t)b * KX + d] = blo(v);
        Xh_[(size_t)b * KX + 1024 + d] = Hh[b * 1024 + d];
        Xl_[(size_t)b * KX + 1024 + d] = Hl[b * 1024 + d];
    }
}

// gates = X[32x2560] * Wg^T[4096x2560] + bias, split-bf16 (3 MFMA chains),
// fused LSTM pointwise. grid 64 blocks, 256 thr, wave-tile M32 x N16, K in 4 chunks of 640.
__global__ __launch_bounds__(256) void k_gates(const bf16* __restrict__ Xh_,
                                               const bf16* __restrict__ Xl_,
                                               const bf16* __restrict__ Wh_,
                                               const bf16* __restrict__ Wl_,
                                               const float* __restrict__ bias,
                                               float* __restrict__ c, float* __restrict__ h,
                                               bf16* __restrict__ Hh, bf16* __restrict__ Hl) {
    int jb = blockIdx.x * 64;
    __shared__ __align__(16) short xh[32][648];
    __shared__ __align__(16) short xl[32][648];
    __shared__ float gl[32][64];
    int tid = threadIdx.x, wave = tid >> 6, lane = tid & 63;
    f32x4 acc0 = {0, 0, 0, 0}, acc1 = {0, 0, 0, 0};
    int jcol = jb + wave * 16 + (lane & 15);
    const short* wrh = (const short*)(Wh_ + (size_t)jcol * KX) + (lane >> 4) * 8;
    const short* wrl = (const short*)(Wl_ + (size_t)jcol * KX) + (lane >> 4) * 8;

    for (int q = 0; q < 4; ++q) {
        __syncthreads();
        for (int i = tid; i < 32 * 80; i += 256) {
            int r = i / 80, cc = i - r * 80;
            ((short8*)&xh[r][0])[cc] = *(const short8*)((const short*)Xh_ + (size_t)r * KX + q * 640 + cc * 8);
            ((short8*)&xl[r][0])[cc] = *(const short8*)((const short*)Xl_ + (size_t)r * KX + q * 640 + cc * 8);
        }
        __syncthreads();
        const short8* wph = (const short8*)(wrh + (size_t)q * 640);
        const short8* wpl = (const short8*)(wrl + (size_t)q * 640);
#pragma unroll 4
        for (int kk = 0; kk < 20; ++kk) {
            int kcol = kk * 32 + (lane >> 4) * 8;
            short8 a0h = *(const short8*)(&xh[lane & 15][kcol]);
            short8 a1h = *(const short8*)(&xh[(lane & 15) + 16][kcol]);
            short8 a0l = *(const short8*)(&xl[lane & 15][kcol]);
            short8 a1l = *(const short8*)(&xl[(lane & 15) + 16][kcol]);
            short8 bh = wph[kk * 4];
            short8 bl = wpl[kk * 4];
            acc0 = __builtin_amdgcn_mfma_f32_16x16x32_bf16(a0h, bh, acc0, 0, 0, 0);
            acc1 = __builtin_amdgcn_mfma_f32_16x16x32_bf16(a1h, bh, acc1, 0, 0, 0);
            acc0 = __builtin_amdgcn_mfma_f32_16x16x32_bf16(a0h, bl, acc0, 0, 0, 0);
            acc1 = __builtin_amdgcn_mfma_f32_16x16x32_bf16(a1h, bl, acc1, 0, 0, 0);
            acc0 = __builtin_amdgcn_mfma_f32_16x16x32_bf16(a0l, bh, acc0, 0, 0, 0);
            acc1 = __builtin_amdgcn_mfma_f32_16x16x32_bf16(a1l, bh, acc1, 0, 0, 0);
        }
    }
    float bcol = bias[jcol];
    int col = wave * 16 + (lane & 15);
#pragma unroll
    for (int r = 0; r < 4; ++r) {
        gl[(lane >> 4) * 4 + r][col]      = acc0[r] + bcol;   // b 0..15
        gl[16 + (lane >> 4) * 4 + r][col] = acc1[r] + bcol;   // b 16..31
    }
    __syncthreads();
    // block covers d in [jb/4, jb/4+16); all 32 b. j' = 4d+g.
    for (int p = tid; p < 512; p += 256) {
        int bb = p & 31, dd = p >> 5;
        float gi = gl[bb][dd * 4 + 0], gf = gl[bb][dd * 4 + 1];
        float gg = gl[bb][dd * 4 + 2], go = gl[bb][dd * 4 + 3];
        int d = (jb >> 2) + dd;
        float cv = c[bb * 1024 + d];
        float cn = sigmoidf_(gf) * cv + sigmoidf_(gi) * tanhf(gg);
        float hn = sigmoidf_(go) * tanhf(cn);
        c[bb * 1024 + d] = cn;
        h[bb * 1024 + d] = hn;
        Hh[bb * 1024 + d] = bhi(hn);
        Hl[bb * 1024 + d] = blo(hn);
    }
}

// p = [ctx | h_t] @ proj_W^T + proj_b -> P hi/lo [(b*64+t)][512].
// Split-bf16 (3 chains). Also gathers e_{t+1} = emb_w[label_t] into X e-part. grid 8 blocks.
__global__ __launch_bounds__(256) void k_proj(const bf16* __restrict__ Xh_,
                                              const bf16* __restrict__ Xl_,
                                              const bf16* __restrict__ Hh_,
                                              const bf16* __restrict__ Hl_,
                                              const bf16* __restrict__ PWh,
                                              const bf16* __restrict__ PWl,
                                              const float* __restrict__ pb,
                                              const float* __restrict__ emb_w,
                                              const int* __restrict__ label,
                                              bf16* __restrict__ Ph, bf16* __restrict__ Pl,
                                              bf16* __restrict__ Xeh, bf16* __restrict__ Xel,
                                              int t) {
    int nb = blockIdx.x * 64;
    __shared__ __align__(16) short xh[32][1032];
    __shared__ __align__(16) short xl[32][1032];
    int tid = threadIdx.x, wave = tid >> 6, lane = tid & 63;
    f32x4 acc0 = {0, 0, 0, 0}, acc1 = {0, 0, 0, 0};
    int ncol = nb + wave * 16 + (lane & 15);
    const short* wrh = (const short*)(PWh + (size_t)ncol * KP) + (lane >> 4) * 8;
    const short* wrl = (const short*)(PWl + (size_t)ncol * KP) + (lane >> 4) * 8;

    for (int half = 0; half < 2; ++half) {
        __syncthreads();
        const short* sh_ = half ? (const short*)Hh_ : (const short*)Xh_;
        const short* sl_ = half ? (const short*)Hl_ : (const short*)Xl_;
        size_t rstride = half ? 1024 : KX;
        for (int i = tid; i < 32 * 128; i += 256) {
            int r = i >> 7, cc = i & 127;
            ((short8*)&xh[r][0])[cc] = *(const short8*)(sh_ + (size_t)r * rstride + cc * 8);
            ((short8*)&xl[r][0])[cc] = *(const short8*)(sl_ + (size_t)r * rstride + cc * 8);
        }
        __syncthreads();
        const short8* wph = (const short8*)(wrh + (size_t)half * 1024);
        const short8* wpl = (const short8*)(wrl + (size_t)half * 1024);
#pragma unroll 4
        for (int kk = 0; kk < 32; ++kk) {
            int kcol = kk * 32 + (lane >> 4) * 8;
            short8 a0h = *(const short8*)(&xh[lane & 15][kcol]);
            short8 a1h = *(const short8*)(&xh[(lane & 15) + 16][kcol]);
            short8 a0l = *(const short8*)(&xl[lane & 15][kcol]);
            short8 a1l = *(const short8*)(&xl[(lane & 15) + 16][kcol]);
            short8 bh = wph[kk * 4];
            short8 bl = wpl[kk * 4];
            acc0 = __builtin_amdgcn_mfma_f32_16x16x32_bf16(a0h, bh, acc0, 0, 0, 0);
            acc1 = __builtin_amdgcn_mfma_f32_16x16x32_bf16(a1h, bh, acc1, 0, 0, 0);
            acc0 = __builtin_amdgcn_mfma_f32_16x16x32_bf16(a0h, bl, acc0, 0, 0, 0);
            acc1 = __builtin_amdgcn_mfma_f32_16x16x32_bf16(a1h, bl, acc1, 0, 0, 0);
            acc0 = __builtin_amdgcn_mfma_f32_16x16x32_bf16(a0l, bh, acc0, 0, 0, 0);
            acc1 = __builtin_amdgcn_mfma_f32_16x16x32_bf16(a1l, bh, acc1, 0, 0, 0);
        }
    }
    float bcol = pb[ncol];
#pragma unroll
    for (int r = 0; r < 4; ++r) {
        int b0 = (lane >> 4) * 4 + r;
        float p0 = acc0[r] + bcol, p1 = acc1[r] + bcol;
        Ph[(size_t)(b0 * 64 + t) * 512 + ncol]        = bhi(p0);
        Pl[(size_t)(b0 * 64 + t) * 512 + ncol]        = blo(p0);
        Ph[(size_t)((b0 + 16) * 64 + t) * 512 + ncol] = bhi(p1);
        Pl[(size_t)((b0 + 16) * 64 + t) * 512 + ncol] = blo(p1);
    }
    if (t < 63) {
        for (int p = tid; p < 2048; p += 256) {
            int bb = blockIdx.x * 4 + (p >> 9);
            int d = p & 511;
            int w = label[bb * 64 + t];
            w = w < 0 ? 0 : (w > V_ - 1 ? V_ - 1 : w);
            float v = emb_w[(size_t)w * 512 + d];
            Xeh[(size_t)bb * KX + 2048 + d] = bhi(v);
            Xel[(size_t)bb * KX + 2048 + d] = blo(v);
        }
    }
}

// OUT[m][v] = P[m][:] . emb_w[v][:],  m = b*64+t. P split hi/lo (2 chains), emb single bf16.
// grid (500, 32): block tile M64 x N64, wave-tile 32x32, K in 2 chunks of 256.
__global__ __launch_bounds__(256) void k_out(const bf16* __restrict__ Ph,
                                             const bf16* __restrict__ Pl,
                                             const bf16* __restrict__ Eb,
                                             float* __restrict__ out) {
    int vb = blockIdx.x * 64;
    int mb = blockIdx.y * 64;
    __shared__ __align__(16) short ph[64][264];
    __shared__ __align__(16) short pl[64][264];
    int tid = threadIdx.x, wave = tid >> 6, lane = tid & 63;
    int wr = (wave >> 1) * 32, wc = (wave & 1) * 32;
    f32x4 acc[2][2] = {{{0, 0, 0, 0}, {0, 0, 0, 0}}, {{0, 0, 0, 0}, {0, 0, 0, 0}}};
    const short* e0 = (const short*)Eb + (size_t)(vb + wc + (lane & 15)) * 512 + (lane >> 4) * 8;
    const short* e1 = e0 + 16 * 512;

    for (int q = 0; q < 2; ++q) {
        __syncthreads();
        for (int i = tid; i < 64 * 32; i += 256) {
            int r = i >> 5, cc = i & 31;
            ((short8*)&ph[r][0])[cc] = *(const short8*)((const short*)Ph + (size_t)(mb + r) * 512 + q * 256 + cc * 8);
            ((short8*)&pl[r][0])[cc] = *(const short8*)((const short*)Pl + (size_t)(mb + r) * 512 + q * 256 + cc * 8);
        }
        __syncthreads();
#pragma unroll
        for (int kk = 0; kk < 8; ++kk) {
            int kcol = kk * 32 + (lane >> 4) * 8;
            short8 a0h = *(const short8*)(&ph[wr + (lane & 15)][kcol]);
            short8 a1h = *(const short8*)(&ph[wr + 16 + (lane & 15)][kcol]);
            short8 a0l = *(const short8*)(&pl[wr + (lane & 15)][kcol]);
            short8 a1l = *(const short8*)(&pl[wr + 16 + (lane & 15)][kcol]);
            short8 b0 = *(const short8*)(e0 + q * 256 + kk * 32);
            short8 b1 = *(const short8*)(e1 + q * 256 + kk * 32);
            acc[0][0] = __builtin_amdgcn_mfma_f32_16x16x32_bf16(a0h, b0, acc[0][0], 0, 0, 0);
            acc[0][1] = __builtin_amdgcn_mfma_f32_16x16x32_bf16(a0h, b1, acc[0][1], 0, 0, 0);
            acc[1][0] = __builtin_amdgcn_mfma_f32_16x16x32_bf16(a1h, b0, acc[1][0], 0, 0, 0);
            acc[1][1] = __builtin_amdgcn_mfma_f32_16x16x32_bf16(a1h, b1, acc[1][1], 0, 0, 0);
            acc[0][0] = __builtin_amdgcn_mfma_f32_16x16x32_bf16(a0l, b0, acc[0][0], 0, 0, 0);
            acc[0][1] = __builtin_amdgcn_mfma_f32_16x16x32_bf16(a0l, b1, acc[0][1], 0, 0, 0);
            acc[1][0] = __builtin_amdgcn_mfma_f32_16x16x32_bf16(a1l, b0, acc[1][0], 0, 0, 0);
            acc[1][1] = __builtin_amdgcn_mfma_f32_16x16x32_bf16(a1l, b1, acc[1][1], 0, 0, 0);
        }
    }
#pragma unroll
    for (int f0 = 0; f0 < 2; ++f0)
#pragma unroll
        for (int f1 = 0; f1 < 2; ++f1)
#pragma unroll
            for (int r = 0; r < 4; ++r) {
                int mm = mb + wr + 16 * f0 + (lane >> 4) * 4 + r;
                int vv = vb + wc + 16 * f1 + (lane & 15);
                out[(size_t)mm * V_ + vv] = acc[f0][f1][r];
            }
}

// ---------------- launcher ----------------

extern "C" void kernel_launch(void* const* d_in, const int* in_sizes, int n_in,
                              void* d_out, int out_size, void* d_ws, size_t ws_size,
                              hipStream_t stream) {
    (void)in_sizes; (void)n_in; (void)out_size; (void)ws_size;
    const float* enc    = (const float*)d_in[0];
    const float* mask   = (const float*)d_in[1];
    const int*   label  = (const int*)d_in[2];
    const float* emb_w  = (const float*)d_in[3];
    const float* W_ih   = (const float*)d_in[4];
    const float* b_ih   = (const float*)d_in[5];
    const float* W_hh   = (const float*)d_in[6];
    const float* b_hh   = (const float*)d_in[7];
    const float* proj_W = (const float*)d_in[8];
    const float* proj_b = (const float*)d_in[9];
    const float* emb0   = (const float*)d_in[10];
    const float* h0     = (const float*)d_in[11];
    const float* c0     = (const float*)d_in[12];
    float* out = (float*)d_out;

    char* w = (char*)d_ws;
    size_t o = 0;
    bf16* Wgh  = (bf16*)(w + o); o += (size_t)4096 * KX * 2;     // 21.0 MB
    bf16* Wgl  = (bf16*)(w + o); o += (size_t)4096 * KX * 2;     // 21.0 MB
    bf16* PWh  = (bf16*)(w + o); o += (size_t)512 * KP * 2;      // 2.1 MB
    bf16* PWl  = (bf16*)(w + o); o += (size_t)512 * KP * 2;      // 2.1 MB
    bf16* Eb   = (bf16*)(w + o); o += (size_t)V_ * 512 * 2;      // 32.8 MB
    float* bias= (float*)(w + o); o += 4096 * 4;
    bf16* Xh   = (bf16*)(w + o); o += (size_t)32 * KX * 2;
    bf16* Xl   = (bf16*)(w + o); o += (size_t)32 * KX * 2;
    bf16* Hh   = (bf16*)(w + o); o += (size_t)32 * 1024 * 2;
    bf16* Hl   = (bf16*)(w + o); o += (size_t)32 * 1024 * 2;
    bf16* Ph   = (bf16*)(w + o); o += (size_t)2048 * 512 * 2;    // 2.1 MB
    bf16* Pl   = (bf16*)(w + o); o += (size_t)2048 * 512 * 2;    // 2.1 MB
    float* hb  = (float*)(w + o); o += (size_t)32 * 1024 * 4;
    float* cb  = (float*)(w + o); o += (size_t)32 * 1024 * 4;
    float* sc  = (float*)(w + o); o += (size_t)32 * 512 * 4;
    // total ~84 MB

    k_build_wg<<<4096, 256, 0, stream>>>(W_ih, W_hh, b_ih, b_hh, Wgh, Wgl, bias);
    k_cvt_split<<<1024, 256, 0, stream>>>(proj_W, PWh, PWl, (long)512 * KP);
    k_cvt<<<8192, 256, 0, stream>>>(emb_w, Eb, (long)V_ * 512);
    k_init<<<32, 256, 0, stream>>>(h0, c0, emb0, hb, cb, Xh, Xl, Hh, Hl);

    for (int t = 0; t < T_; ++t) {
        k_score<<<dim3(32, 8), 256, 0, stream>>>(enc, mask, hb, sc);
        k_ctx  <<<dim3(32, 8), 256, 0, stream>>>(enc, sc, Hh, Hl, Xh, Xl);
        k_gates<<<64, 256, 0, stream>>>(Xh, Xl, Wgh, Wgl, bias, cb, hb, Hh, Hl);
        k_proj <<<8, 256, 0, stream>>>(Xh, Xl, Hh, Hl, PWh, PWl, proj_b, emb_w, label,
                                       Ph, Pl, Xh, Xl, t);
    }
    k_out<<<dim3(500, 32), 256, 0, stream>>>(Ph, Pl, Eb, out);
}

// Round 3
// 4440.784 us; speedup vs baseline: 1.4899x; 1.4899x over previous
//
#include <hip/hip_runtime.h>
#include <hip/hip_bf16.h>

// Decoder: attention + LSTMCell + proj + vocab scoring.
// B=32, S=512, T=64, DENC=DHID=1024, DEMB=512, V=32000.
// Precision: recurrent state f32; GEMMs split-bf16 (hi/lo, 3 MFMA chains).
// Structure: 3 dispatches/step: [proj(t-1)+score(t)] -> [ctx] -> [gates].
// Vocab GEMM hoisted to one dispatch at the end.

#define B_   32
#define S_   512
#define T_   64
#define DENC 1024
#define DHID 1024
#define DEMB 512
#define V_   32000
#define KX   2560   // X row: [ctx 1024 | h 1024 | e 512]
#define KP   2048   // proj K: [ctx | h]

using short8 = __attribute__((ext_vector_type(8))) short;
using f32x4  = __attribute__((ext_vector_type(4))) float;
typedef __hip_bfloat16 bf16;

__device__ __forceinline__ float sigmoidf_(float x) { return 1.0f / (1.0f + expf(-x)); }
__device__ __forceinline__ bf16 bhi(float x) { return __float2bfloat16(x); }
__device__ __forceinline__ bf16 blo(float x) {
    return __float2bfloat16(x - __bfloat162float(__float2bfloat16(x)));
}

#define MFMA(a, b, c) __builtin_amdgcn_mfma_f32_16x16x32_bf16((a), (b), (c), 0, 0, 0)

// ---------------- setup kernels ----------------

// Wg rows reordered j' = d*4 + gate so LSTM pointwise fuses into gates epilogue.
__global__ void k_build_wg(const float* __restrict__ W_ih, const float* __restrict__ W_hh,
                           const float* __restrict__ b_ih, const float* __restrict__ b_hh,
                           bf16* __restrict__ Wh, bf16* __restrict__ Wl, float* __restrict__ bias) {
    int jp = blockIdx.x;            // 0..4095
    int g = jp & 3, d = jp >> 2;
    int j = g * 1024 + d;           // source row (torch gate order i,f,g,o)
    const float* wi = W_ih + (size_t)j * 1536;
    const float* wh = W_hh + (size_t)j * 1024;
    bf16* dh = Wh + (size_t)jp * KX;
    bf16* dl = Wl + (size_t)jp * KX;
    for (int i = threadIdx.x; i < 1024; i += 256) { float v = wi[i];      dh[i] = bhi(v);        dl[i] = blo(v); }
    for (int i = threadIdx.x; i < 1024; i += 256) { float v = wh[i];      dh[1024+i] = bhi(v);   dl[1024+i] = blo(v); }
    for (int i = threadIdx.x; i < 512;  i += 256) { float v = wi[1024+i]; dh[2048+i] = bhi(v);   dl[2048+i] = blo(v); }
    if (threadIdx.x == 0) bias[jp] = b_ih[j] + b_hh[j];
}

__global__ void k_cvt(const float* __restrict__ src, bf16* __restrict__ dst, long n) {
    long i = (long)blockIdx.x * blockDim.x + threadIdx.x;
    long stride = (long)gridDim.x * blockDim.x;
    for (; i < n; i += stride) dst[i] = __float2bfloat16(src[i]);
}

__global__ void k_cvt_split(const float* __restrict__ src, bf16* __restrict__ dh,
                            bf16* __restrict__ dl, long n) {
    long i = (long)blockIdx.x * blockDim.x + threadIdx.x;
    long stride = (long)gridDim.x * blockDim.x;
    for (; i < n; i += stride) { float v = src[i]; dh[i] = bhi(v); dl[i] = blo(v); }
}

__global__ void k_init(const float* __restrict__ h0, const float* __restrict__ c0,
                       const float* __restrict__ emb0,
                       float* __restrict__ h, float* __restrict__ c,
                       bf16* __restrict__ Xh_, bf16* __restrict__ Xl_) {
    int b = blockIdx.x;   // 32 blocks
    for (int d = threadIdx.x; d < 1024; d += 256) {
        float v = h0[d];
        h[b * 1024 + d] = v;
        c[b * 1024 + d] = c0[d];
        Xh_[(size_t)b * KX + 1024 + d] = bhi(v);
        Xl_[(size_t)b * KX + 1024 + d] = blo(v);
    }
    for (int d = threadIdx.x; d < 512; d += 256) {
        float v = emb0[d];
        Xh_[(size_t)b * KX + 2048 + d] = bhi(v);
        Xl_[(size_t)b * KX + 2048 + d] = blo(v);
    }
}

// ---------------- per-step kernels ----------------

// Combined dispatch: blocks 0..31 do proj for step t-1 (if t>0);
// blocks 32..287 do score for step t (if t<64). These are independent.
//
// proj: p = X[:, 0:2048] @ PW^T + pb  (split-bf16, 3 chains, no-LDS streaming,
//       4 waves K-split 4x512, LDS reduce), writes Ph/Pl at m = b*64+(t-1);
//       also gathers e_t = emb_w[label_{t-1}] into X e-part.
// score: score[b][s] = dot(enc[b][s], h[b]) - (1-mask)*1e20.
__global__ __launch_bounds__(256) void k_ps(
    const float* __restrict__ enc, const float* __restrict__ mask,
    const float* __restrict__ h, float* __restrict__ score,
    bf16* __restrict__ Xh_, bf16* __restrict__ Xl_,
    const bf16* __restrict__ PWh, const bf16* __restrict__ PWl,
    const float* __restrict__ pb, const float* __restrict__ emb_w,
    const int* __restrict__ label,
    bf16* __restrict__ Ph, bf16* __restrict__ Pl, int t)
{
    __shared__ float hs[1024];
    __shared__ float pr[4][32][17];
    int bid = blockIdx.x;
    int tid = threadIdx.x, wave = tid >> 6, lane = tid & 63;

    if (bid < 32) {
        if (t == 0) return;
        int tp = t - 1;
        int nb = bid * 16;
        int ncol = nb + (lane & 15);
        int kc = wave * 512;
        const short* xhp = (const short*)Xh_;
        const short* xlp = (const short*)Xl_;
        const short* wrh = (const short*)PWh + (size_t)ncol * KP + kc + (lane >> 4) * 8;
        const short* wrl = (const short*)PWl + (size_t)ncol * KP + kc + (lane >> 4) * 8;
        size_t arow0 = (size_t)(lane & 15) * KX + kc + (lane >> 4) * 8;
        size_t arow1 = (size_t)((lane & 15) + 16) * KX + kc + (lane >> 4) * 8;
        f32x4 acc0 = {0, 0, 0, 0}, acc1 = {0, 0, 0, 0};
#pragma unroll 4
        for (int kk = 0; kk < 16; ++kk) {
            int ko = kk * 32;
            short8 a0h = *(const short8*)(xhp + arow0 + ko);
            short8 a1h = *(const short8*)(xhp + arow1 + ko);
            short8 a0l = *(const short8*)(xlp + arow0 + ko);
            short8 a1l = *(const short8*)(xlp + arow1 + ko);
            short8 bh = *(const short8*)(wrh + ko);
            short8 bl = *(const short8*)(wrl + ko);
            acc0 = MFMA(a0h, bh, acc0); acc1 = MFMA(a1h, bh, acc1);
            acc0 = MFMA(a0h, bl, acc0); acc1 = MFMA(a1h, bl, acc1);
            acc0 = MFMA(a0l, bh, acc0); acc1 = MFMA(a1l, bh, acc1);
        }
#pragma unroll
        for (int r = 0; r < 4; ++r) {
            pr[wave][(lane >> 4) * 4 + r][lane & 15]      = acc0[r];
            pr[wave][16 + (lane >> 4) * 4 + r][lane & 15] = acc1[r];
        }
        __syncthreads();
        for (int p = tid; p < 512; p += 256) {
            int bb = p >> 4, col = p & 15;
            float v = pr[0][bb][col] + pr[1][bb][col] + pr[2][bb][col] + pr[3][bb][col]
                      + pb[nb + col];
            size_t mi = (size_t)(bb * 64 + tp) * 512 + nb + col;
            Ph[mi] = bhi(v);
            Pl[mi] = blo(v);
        }
        // gather e_{tp+1} = emb_w[label[:, tp]] for batch b = bid into X e-part
        int b = bid;
        int wd = label[b * 64 + tp];
        wd = wd < 0 ? 0 : (wd > V_ - 1 ? V_ - 1 : wd);
        const float* ew = emb_w + (size_t)wd * 512;
        for (int d = tid; d < 512; d += 256) {
            float v = ew[d];
            Xh_[(size_t)b * KX + 2048 + d] = bhi(v);
            Xl_[(size_t)b * KX + 2048 + d] = blo(v);
        }
        return;
    }

    if (t >= T_) return;
    int b = (bid - 32) >> 3, scb = (bid - 32) & 7;
    ((float4*)hs)[tid] = ((const float4*)(h + b * 1024))[tid];
    __syncthreads();
    const float* encb = enc + (size_t)b * S_ * DENC;
    const float4* hs4 = (const float4*)hs;
    for (int i = 0; i < 16; ++i) {
        int s = scb * 64 + wave * 16 + i;
        const float4* row = (const float4*)(encb + (size_t)s * DENC);
        float acc = 0.f;
#pragma unroll
        for (int r = 0; r < 4; ++r) {
            float4 e4 = row[r * 64 + lane];
            float4 h4 = hs4[r * 64 + lane];
            acc = fmaf(e4.x, h4.x, acc); acc = fmaf(e4.y, h4.y, acc);
            acc = fmaf(e4.z, h4.z, acc); acc = fmaf(e4.w, h4.w, acc);
        }
#pragma unroll
        for (int off = 32; off; off >>= 1) acc += __shfl_xor(acc, off, 64);
        if (lane == 0) score[b * S_ + s] = acc - (1.0f - mask[b * S_ + s]) * 1e20f;
    }
}

// softmax (recomputed per block, f32) + ctx accumulation -> X ctx part (split bf16).
// grid (32,4): block (b, d-chunk of 256). 4 waves split s 4x128; float4 loads;
// LDS reduce across waves.
__global__ __launch_bounds__(256) void k_ctx(const float* __restrict__ enc,
                                             const float* __restrict__ score,
                                             bf16* __restrict__ Xh_, bf16* __restrict__ Xl_) {
    __shared__ float attn[512];
    __shared__ float red[8];
    __shared__ float part[4][256];
    int b = blockIdx.x, dc = blockIdx.y;
    int tid = threadIdx.x, wave = tid >> 6, lane = tid & 63;

    float s0 = score[b * 512 + tid], s1 = score[b * 512 + 256 + tid];
    float m = fmaxf(s0, s1);
#pragma unroll
    for (int off = 32; off; off >>= 1) m = fmaxf(m, __shfl_xor(m, off, 64));
    if (lane == 0) red[wave] = m;
    __syncthreads();
    m = fmaxf(fmaxf(red[0], red[1]), fmaxf(red[2], red[3]));
    float e0 = expf(s0 - m), e1 = expf(s1 - m);
    float sum = e0 + e1;
#pragma unroll
    for (int off = 32; off; off >>= 1) sum += __shfl_xor(sum, off, 64);
    if (lane == 0) red[4 + wave] = sum;
    __syncthreads();
    float inv = 1.0f / (red[4] + red[5] + red[6] + red[7]);
    attn[tid] = e0 * inv;
    attn[256 + tid] = e1 * inv;
    __syncthreads();

    int d = dc * 256 + lane * 4;
    const float* ep = enc + (size_t)b * S_ * DENC + d;
    float ax = 0.f, ay = 0.f, az = 0.f, aw = 0.f;
    int sbeg = wave * 128;
#pragma unroll 16
    for (int s = sbeg; s < sbeg + 128; ++s) {
        float4 e4 = *(const float4*)(ep + (size_t)s * DENC);
        float a = attn[s];
        ax = fmaf(a, e4.x, ax); ay = fmaf(a, e4.y, ay);
        az = fmaf(a, e4.z, az); aw = fmaf(a, e4.w, aw);
    }
    part[wave][lane * 4 + 0] = ax;
    part[wave][lane * 4 + 1] = ay;
    part[wave][lane * 4 + 2] = az;
    part[wave][lane * 4 + 3] = aw;
    __syncthreads();
    float v = part[0][tid] + part[1][tid] + part[2][tid] + part[3][tid];
    size_t xi = (size_t)b * KX + dc * 256 + tid;
    Xh_[xi] = bhi(v);
    Xl_[xi] = blo(v);
}

// gates = X[32x2560] @ Wg^T[4096x2560] + bias (split-bf16, 3 chains), fused LSTM
// pointwise. grid 128 x 256thr: block = 32 cols; waves = 2 col-groups x 2 K-halves.
// No LDS staging: A fragments stream from global X (L2-hot), B from Wg.
// Epilogue writes h into X h-part directly (and f32 h for score).
__global__ __launch_bounds__(256) void k_gates(
    const bf16* __restrict__ Xh_, const bf16* __restrict__ Xl_,
    const bf16* __restrict__ Wh_, const bf16* __restrict__ Wl_,
    const float* __restrict__ bias,
    float* __restrict__ c, float* __restrict__ h,
    bf16* __restrict__ XhO, bf16* __restrict__ XlO)
{
    __shared__ float gl2[2][32][33];
    int jb = blockIdx.x * 32;
    int tid = threadIdx.x, wave = tid >> 6, lane = tid & 63;
    int ng = wave & 1, kh = wave >> 1;
    int jcol = jb + ng * 16 + (lane & 15);
    const short* xhp = (const short*)Xh_ + kh * 1280 + (lane >> 4) * 8;
    const short* xlp = (const short*)Xl_ + kh * 1280 + (lane >> 4) * 8;
    const short* wrh = (const short*)Wh_ + (size_t)jcol * KX + kh * 1280 + (lane >> 4) * 8;
    const short* wrl = (const short*)Wl_ + (size_t)jcol * KX + kh * 1280 + (lane >> 4) * 8;
    size_t arow0 = (size_t)(lane & 15) * KX;
    size_t arow1 = (size_t)((lane & 15) + 16) * KX;
    f32x4 acc0 = {0, 0, 0, 0}, acc1 = {0, 0, 0, 0};
#pragma unroll 4
    for (int kk = 0; kk < 40; ++kk) {
        int ko = kk * 32;
        short8 a0h = *(const short8*)(xhp + arow0 + ko);
        short8 a1h = *(const short8*)(xhp + arow1 + ko);
        short8 a0l = *(const short8*)(xlp + arow0 + ko);
        short8 a1l = *(const short8*)(xlp + arow1 + ko);
        short8 bh = *(const short8*)(wrh + ko);
        short8 bl = *(const short8*)(wrl + ko);
        acc0 = MFMA(a0h, bh, acc0); acc1 = MFMA(a1h, bh, acc1);
        acc0 = MFMA(a0h, bl, acc0); acc1 = MFMA(a1h, bl, acc1);
        acc0 = MFMA(a0l, bh, acc0); acc1 = MFMA(a1l, bh, acc1);
    }
#pragma unroll
    for (int r = 0; r < 4; ++r) {
        gl2[kh][(lane >> 4) * 4 + r][ng * 16 + (lane & 15)]      = acc0[r];
        gl2[kh][16 + (lane >> 4) * 4 + r][ng * 16 + (lane & 15)] = acc1[r];
    }
    __syncthreads();
    // 256 threads = 32 b x 8 d. cols jb..jb+32 are j' = 4d+g for d in [jb/4, jb/4+8).
    int bb = tid & 31, dd = tid >> 5;
    int cb = dd * 4;
    float gi = gl2[0][bb][cb + 0] + gl2[1][bb][cb + 0] + bias[jb + cb + 0];
    float gf = gl2[0][bb][cb + 1] + gl2[1][bb][cb + 1] + bias[jb + cb + 1];
    float gg = gl2[0][bb][cb + 2] + gl2[1][bb][cb + 2] + bias[jb + cb + 2];
    float go = gl2[0][bb][cb + 3] + gl2[1][bb][cb + 3] + bias[jb + cb + 3];
    int d = (jb >> 2) + dd;
    float cv = c[bb * 1024 + d];
    float cn = sigmoidf_(gf) * cv + sigmoidf_(gi) * tanhf(gg);
    float hn = sigmoidf_(go) * tanhf(cn);
    c[bb * 1024 + d] = cn;
    h[bb * 1024 + d] = hn;
    XhO[(size_t)bb * KX + 1024 + d] = bhi(hn);
    XlO[(size_t)bb * KX + 1024 + d] = blo(hn);
}

// OUT[m][v] = P[m][:] . emb_w[v][:],  m = b*64+t. P split hi/lo (2 chains), emb single bf16.
// grid (500, 32): block tile M64 x N64, wave-tile 32x32, K in 2 chunks of 256.
__global__ __launch_bounds__(256) void k_out(const bf16* __restrict__ Ph,
                                             const bf16* __restrict__ Pl,
                                             const bf16* __restrict__ Eb,
                                             float* __restrict__ out) {
    int vb = blockIdx.x * 64;
    int mb = blockIdx.y * 64;
    __shared__ __align__(16) short ph[64][264];
    __shared__ __align__(16) short pl[64][264];
    int tid = threadIdx.x, wave = tid >> 6, lane = tid & 63;
    int wr = (wave >> 1) * 32, wc = (wave & 1) * 32;
    f32x4 acc[2][2] = {{{0, 0, 0, 0}, {0, 0, 0, 0}}, {{0, 0, 0, 0}, {0, 0, 0, 0}}};
    const short* e0 = (const short*)Eb + (size_t)(vb + wc + (lane & 15)) * 512 + (lane >> 4) * 8;
    const short* e1 = e0 + 16 * 512;

    for (int q = 0; q < 2; ++q) {
        __syncthreads();
        for (int i = tid; i < 64 * 32; i += 256) {
            int r = i >> 5, cc = i & 31;
            ((short8*)&ph[r][0])[cc] = *(const short8*)((const short*)Ph + (size_t)(mb + r) * 512 + q * 256 + cc * 8);
            ((short8*)&pl[r][0])[cc] = *(const short8*)((const short*)Pl + (size_t)(mb + r) * 512 + q * 256 + cc * 8);
        }
        __syncthreads();
#pragma unroll
        for (int kk = 0; kk < 8; ++kk) {
            int kcol = kk * 32 + (lane >> 4) * 8;
            short8 a0h = *(const short8*)(&ph[wr + (lane & 15)][kcol]);
            short8 a1h = *(const short8*)(&ph[wr + 16 + (lane & 15)][kcol]);
            short8 a0l = *(const short8*)(&pl[wr + (lane & 15)][kcol]);
            short8 a1l = *(const short8*)(&pl[wr + 16 + (lane & 15)][kcol]);
            short8 b0 = *(const short8*)(e0 + q * 256 + kk * 32);
            short8 b1 = *(const short8*)(e1 + q * 256 + kk * 32);
            acc[0][0] = MFMA(a0h, b0, acc[0][0]);
            acc[0][1] = MFMA(a0h, b1, acc[0][1]);
            acc[1][0] = MFMA(a1h, b0, acc[1][0]);
            acc[1][1] = MFMA(a1h, b1, acc[1][1]);
            acc[0][0] = MFMA(a0l, b0, acc[0][0]);
            acc[0][1] = MFMA(a0l, b1, acc[0][1]);
            acc[1][0] = MFMA(a1l, b0, acc[1][0]);
            acc[1][1] = MFMA(a1l, b1, acc[1][1]);
        }
    }
#pragma unroll
    for (int f0 = 0; f0 < 2; ++f0)
#pragma unroll
        for (int f1 = 0; f1 < 2; ++f1)
#pragma unroll
            for (int r = 0; r < 4; ++r) {
                int mm = mb + wr + 16 * f0 + (lane >> 4) * 4 + r;
                int vv = vb + wc + 16 * f1 + (lane & 15);
                out[(size_t)mm * V_ + vv] = acc[f0][f1][r];
            }
}

// ---------------- launcher ----------------

extern "C" void kernel_launch(void* const* d_in, const int* in_sizes, int n_in,
                              void* d_out, int out_size, void* d_ws, size_t ws_size,
                              hipStream_t stream) {
    (void)in_sizes; (void)n_in; (void)out_size; (void)ws_size;
    const float* enc    = (const float*)d_in[0];
    const float* mask   = (const float*)d_in[1];
    const int*   label  = (const int*)d_in[2];
    const float* emb_w  = (const float*)d_in[3];
    const float* W_ih   = (const float*)d_in[4];
    const float* b_ih   = (const float*)d_in[5];
    const float* W_hh   = (const float*)d_in[6];
    const float* b_hh   = (const float*)d_in[7];
    const float* proj_W = (const float*)d_in[8];
    const float* proj_b = (const float*)d_in[9];
    const float* emb0   = (const float*)d_in[10];
    const float* h0     = (const float*)d_in[11];
    const float* c0     = (const float*)d_in[12];
    float* out = (float*)d_out;

    char* w = (char*)d_ws;
    size_t o = 0;
    bf16* Wgh  = (bf16*)(w + o); o += (size_t)4096 * KX * 2;     // 21.0 MB
    bf16* Wgl  = (bf16*)(w + o); o += (size_t)4096 * KX * 2;     // 21.0 MB
    bf16* PWh  = (bf16*)(w + o); o += (size_t)512 * KP * 2;      // 2.1 MB
    bf16* PWl  = (bf16*)(w + o); o += (size_t)512 * KP * 2;      // 2.1 MB
    bf16* Eb   = (bf16*)(w + o); o += (size_t)V_ * 512 * 2;      // 32.8 MB
    float* bias= (float*)(w + o); o += 4096 * 4;
    bf16* Xh   = (bf16*)(w + o); o += (size_t)32 * KX * 2;
    bf16* Xl   = (bf16*)(w + o); o += (size_t)32 * KX * 2;
    bf16* Ph   = (bf16*)(w + o); o += (size_t)2048 * 512 * 2;    // 2.1 MB
    bf16* Pl   = (bf16*)(w + o); o += (size_t)2048 * 512 * 2;    // 2.1 MB
    float* hb  = (float*)(w + o); o += (size_t)32 * 1024 * 4;
    float* cb  = (float*)(w + o); o += (size_t)32 * 1024 * 4;
    float* sc  = (float*)(w + o); o += (size_t)32 * 512 * 4;
    // total ~84 MB

    k_build_wg<<<4096, 256, 0, stream>>>(W_ih, W_hh, b_ih, b_hh, Wgh, Wgl, bias);
    k_cvt_split<<<1024, 256, 0, stream>>>(proj_W, PWh, PWl, (long)512 * KP);
    k_cvt<<<8192, 256, 0, stream>>>(emb_w, Eb, (long)V_ * 512);
    k_init<<<32, 256, 0, stream>>>(h0, c0, emb0, hb, cb, Xh, Xl);

    for (int t = 0; t <= T_; ++t) {
        k_ps<<<288, 256, 0, stream>>>(enc, mask, hb, sc, Xh, Xl, PWh, PWl, proj_b,
                                      emb_w, label, Ph, Pl, t);
        if (t < T_) {
            k_ctx  <<<dim3(32, 4), 256, 0, stream>>>(enc, sc, Xh, Xl);
            k_gates<<<128, 256, 0, stream>>>(Xh, Xl, Wgh, Wgl, bias, cb, hb, Xh, Xl);
        }
    }
    k_out<<<dim3(500, 32), 256, 0, stream>>>(Ph, Pl, Eb, out);
}

// Round 4
// 3456.589 us; speedup vs baseline: 1.9142x; 1.2847x over previous
//
#include <hip/hip_runtime.h>
#include <hip/hip_bf16.h>

// Decoder: attention + LSTMCell + proj + vocab scoring.
// B=32, S=512, T=64, DENC=DHID=1024, DEMB=512, V=32000.
// Precision: recurrent state f32; GEMMs split-bf16 (hi/lo, 3 MFMA chains).
// Structure: 3 dispatches/step: [proj(t-1)+score(t)] -> [ctx] -> [gates].
// Vocab GEMM hoisted to one dispatch at the end.
// R4: occupancy fixes (256+ blocks/kernel, deeper load pipelines),
//     k_out nontemporal stores + m-inner grid ordering.

#define B_   32
#define S_   512
#define T_   64
#define DENC 1024
#define DHID 1024
#define DEMB 512
#define V_   32000
#define KX   2560   // X row: [ctx 1024 | h 1024 | e 512]
#define KP   2048   // proj K: [ctx | h]

using short8 = __attribute__((ext_vector_type(8))) short;
using f32x4  = __attribute__((ext_vector_type(4))) float;
typedef __hip_bfloat16 bf16;

__device__ __forceinline__ float sigmoidf_(float x) { return 1.0f / (1.0f + expf(-x)); }
__device__ __forceinline__ bf16 bhi(float x) { return __float2bfloat16(x); }
__device__ __forceinline__ bf16 blo(float x) {
    return __float2bfloat16(x - __bfloat162float(__float2bfloat16(x)));
}

#define MFMA(a, b, c) __builtin_amdgcn_mfma_f32_16x16x32_bf16((a), (b), (c), 0, 0, 0)

// ---------------- setup kernels ----------------

// Wg rows reordered j' = d*4 + gate so LSTM pointwise fuses into gates epilogue.
__global__ void k_build_wg(const float* __restrict__ W_ih, const float* __restrict__ W_hh,
                           const float* __restrict__ b_ih, const float* __restrict__ b_hh,
                           bf16* __restrict__ Wh, bf16* __restrict__ Wl, float* __restrict__ bias) {
    int jp = blockIdx.x;            // 0..4095
    int g = jp & 3, d = jp >> 2;
    int j = g * 1024 + d;           // source row (torch gate order i,f,g,o)
    const float* wi = W_ih + (size_t)j * 1536;
    const float* wh = W_hh + (size_t)j * 1024;
    bf16* dh = Wh + (size_t)jp * KX;
    bf16* dl = Wl + (size_t)jp * KX;
    for (int i = threadIdx.x; i < 1024; i += 256) { float v = wi[i];      dh[i] = bhi(v);        dl[i] = blo(v); }
    for (int i = threadIdx.x; i < 1024; i += 256) { float v = wh[i];      dh[1024+i] = bhi(v);   dl[1024+i] = blo(v); }
    for (int i = threadIdx.x; i < 512;  i += 256) { float v = wi[1024+i]; dh[2048+i] = bhi(v);   dl[2048+i] = blo(v); }
    if (threadIdx.x == 0) bias[jp] = b_ih[j] + b_hh[j];
}

__global__ void k_cvt(const float* __restrict__ src, bf16* __restrict__ dst, long n) {
    long i = (long)blockIdx.x * blockDim.x + threadIdx.x;
    long stride = (long)gridDim.x * blockDim.x;
    for (; i < n; i += stride) dst[i] = __float2bfloat16(src[i]);
}

__global__ void k_cvt_split(const float* __restrict__ src, bf16* __restrict__ dh,
                            bf16* __restrict__ dl, long n) {
    long i = (long)blockIdx.x * blockDim.x + threadIdx.x;
    long stride = (long)gridDim.x * blockDim.x;
    for (; i < n; i += stride) { float v = src[i]; dh[i] = bhi(v); dl[i] = blo(v); }
}

__global__ void k_init(const float* __restrict__ h0, const float* __restrict__ c0,
                       const float* __restrict__ emb0,
                       float* __restrict__ h, float* __restrict__ c,
                       bf16* __restrict__ Xh_, bf16* __restrict__ Xl_) {
    int b = blockIdx.x;   // 32 blocks
    for (int d = threadIdx.x; d < 1024; d += 256) {
        float v = h0[d];
        h[b * 1024 + d] = v;
        c[b * 1024 + d] = c0[d];
        Xh_[(size_t)b * KX + 1024 + d] = bhi(v);
        Xl_[(size_t)b * KX + 1024 + d] = blo(v);
    }
    for (int d = threadIdx.x; d < 512; d += 256) {
        float v = emb0[d];
        Xh_[(size_t)b * KX + 2048 + d] = bhi(v);
        Xl_[(size_t)b * KX + 2048 + d] = blo(v);
    }
}

// ---------------- per-step kernels ----------------

// Combined dispatch: blocks 0..31 do proj for step t-1 (if t>0);
// blocks 32..543 do score for step t (if t<64). Independent work.
__global__ __launch_bounds__(256) void k_ps(
    const float* __restrict__ enc, const float* __restrict__ mask,
    const float* __restrict__ h, float* __restrict__ score,
    bf16* __restrict__ Xh_, bf16* __restrict__ Xl_,
    const bf16* __restrict__ PWh, const bf16* __restrict__ PWl,
    const float* __restrict__ pb, const float* __restrict__ emb_w,
    const int* __restrict__ label,
    bf16* __restrict__ Ph, bf16* __restrict__ Pl, int t)
{
    __shared__ float hs[1024];
    __shared__ float pr[4][32][17];
    int bid = blockIdx.x;
    int tid = threadIdx.x, wave = tid >> 6, lane = tid & 63;

    if (bid < 32) {
        // ---- proj for step t-1 (split-bf16, 3 chains, 4-way K-split) ----
        if (t == 0) return;
        int tp = t - 1;
        int nb = bid * 16;
        int ncol = nb + (lane & 15);
        int kc = wave * 512;
        const short* xhp = (const short*)Xh_;
        const short* xlp = (const short*)Xl_;
        const short* wrh = (const short*)PWh + (size_t)ncol * KP + kc + (lane >> 4) * 8;
        const short* wrl = (const short*)PWl + (size_t)ncol * KP + kc + (lane >> 4) * 8;
        size_t arow0 = (size_t)(lane & 15) * KX + kc + (lane >> 4) * 8;
        size_t arow1 = (size_t)((lane & 15) + 16) * KX + kc + (lane >> 4) * 8;
        f32x4 acc0 = {0, 0, 0, 0}, acc1 = {0, 0, 0, 0};
#pragma unroll 4
        for (int kk = 0; kk < 16; ++kk) {
            int ko = kk * 32;
            short8 a0h = *(const short8*)(xhp + arow0 + ko);
            short8 a1h = *(const short8*)(xhp + arow1 + ko);
            short8 a0l = *(const short8*)(xlp + arow0 + ko);
            short8 a1l = *(const short8*)(xlp + arow1 + ko);
            short8 bh = *(const short8*)(wrh + ko);
            short8 bl = *(const short8*)(wrl + ko);
            acc0 = MFMA(a0h, bh, acc0); acc1 = MFMA(a1h, bh, acc1);
            acc0 = MFMA(a0h, bl, acc0); acc1 = MFMA(a1h, bl, acc1);
            acc0 = MFMA(a0l, bh, acc0); acc1 = MFMA(a1l, bh, acc1);
        }
#pragma unroll
        for (int r = 0; r < 4; ++r) {
            pr[wave][(lane >> 4) * 4 + r][lane & 15]      = acc0[r];
            pr[wave][16 + (lane >> 4) * 4 + r][lane & 15] = acc1[r];
        }
        __syncthreads();
        for (int p = tid; p < 512; p += 256) {
            int bb = p >> 4, col = p & 15;
            float v = pr[0][bb][col] + pr[1][bb][col] + pr[2][bb][col] + pr[3][bb][col]
                      + pb[nb + col];
            size_t mi = (size_t)(bb * 64 + tp) * 512 + nb + col;
            Ph[mi] = bhi(v);
            Pl[mi] = blo(v);
        }
        // gather e_t = emb_w[label[:, tp]] for batch b = bid into X e-part
        int b = bid;
        int wd = label[b * 64 + tp];
        wd = wd < 0 ? 0 : (wd > V_ - 1 ? V_ - 1 : wd);
        const float* ew = emb_w + (size_t)wd * 512;
        for (int d = tid; d < 512; d += 256) {
            float v = ew[d];
            Xh_[(size_t)b * KX + 2048 + d] = bhi(v);
            Xl_[(size_t)b * KX + 2048 + d] = blo(v);
        }
        return;
    }

    // ---- score for step t: 512 blocks, 32 rows each ----
    if (t >= T_) return;
    int bid2 = bid - 32;
    int b = bid2 >> 4, scb = bid2 & 15;
    ((float4*)hs)[tid] = ((const float4*)(h + b * 1024))[tid];
    __syncthreads();
    const float* encb = enc + (size_t)b * S_ * DENC;
    const float4* hs4 = (const float4*)hs;
    int sbase = scb * 32 + wave * 8;
    for (int i = 0; i < 8; i += 2) {
        int s0i = sbase + i, s1i = sbase + i + 1;
        const float4* r0 = (const float4*)(encb + (size_t)s0i * DENC);
        const float4* r1 = (const float4*)(encb + (size_t)s1i * DENC);
        float a0 = 0.f, a1 = 0.f;
#pragma unroll
        for (int r = 0; r < 4; ++r) {
            float4 e0 = r0[r * 64 + lane];
            float4 e1 = r1[r * 64 + lane];
            float4 h4 = hs4[r * 64 + lane];
            a0 = fmaf(e0.x, h4.x, a0); a0 = fmaf(e0.y, h4.y, a0);
            a0 = fmaf(e0.z, h4.z, a0); a0 = fmaf(e0.w, h4.w, a0);
            a1 = fmaf(e1.x, h4.x, a1); a1 = fmaf(e1.y, h4.y, a1);
            a1 = fmaf(e1.z, h4.z, a1); a1 = fmaf(e1.w, h4.w, a1);
        }
#pragma unroll
        for (int off = 32; off; off >>= 1) {
            a0 += __shfl_xor(a0, off, 64);
            a1 += __shfl_xor(a1, off, 64);
        }
        if (lane == 0) {
            score[b * S_ + s0i] = a0 - (1.0f - mask[b * S_ + s0i]) * 1e20f;
            score[b * S_ + s1i] = a1 - (1.0f - mask[b * S_ + s1i]) * 1e20f;
        }
    }
}

// softmax (recomputed per block, f32) + ctx accumulation -> X ctx part (split bf16).
// grid (32,8): block (b, 128-d chunk). Thread owns float4 of d; 8-way s-split;
// LDS reduce across the 8 s-groups.
__global__ __launch_bounds__(256) void k_ctx(const float* __restrict__ enc,
                                             const float* __restrict__ score,
                                             bf16* __restrict__ Xh_, bf16* __restrict__ Xl_) {
    __shared__ float attn[512];
    __shared__ float red[8];
    __shared__ float part[8][128];
    int b = blockIdx.x, dc = blockIdx.y;
    int tid = threadIdx.x, wave = tid >> 6, lane = tid & 63;

    float s0 = score[b * 512 + tid], s1 = score[b * 512 + 256 + tid];
    float m = fmaxf(s0, s1);
#pragma unroll
    for (int off = 32; off; off >>= 1) m = fmaxf(m, __shfl_xor(m, off, 64));
    if (lane == 0) red[wave] = m;
    __syncthreads();
    m = fmaxf(fmaxf(red[0], red[1]), fmaxf(red[2], red[3]));
    float e0 = expf(s0 - m), e1 = expf(s1 - m);
    float sum = e0 + e1;
#pragma unroll
    for (int off = 32; off; off >>= 1) sum += __shfl_xor(sum, off, 64);
    if (lane == 0) red[4 + wave] = sum;
    __syncthreads();
    float inv = 1.0f / (red[4] + red[5] + red[6] + red[7]);
    attn[tid] = e0 * inv;
    attn[256 + tid] = e1 * inv;
    __syncthreads();

    int sg = tid >> 5, l32 = tid & 31;
    int d = dc * 128 + l32 * 4;
    const float* ep = enc + (size_t)b * S_ * DENC + d;
    float ax = 0.f, ay = 0.f, az = 0.f, aw = 0.f;
    int sbeg = sg * 64;
#pragma unroll 8
    for (int s = sbeg; s < sbeg + 64; ++s) {
        float4 e4 = *(const float4*)(ep + (size_t)s * DENC);
        float a = attn[s];
        ax = fmaf(a, e4.x, ax); ay = fmaf(a, e4.y, ay);
        az = fmaf(a, e4.z, az); aw = fmaf(a, e4.w, aw);
    }
    part[sg][l32 * 4 + 0] = ax;
    part[sg][l32 * 4 + 1] = ay;
    part[sg][l32 * 4 + 2] = az;
    part[sg][l32 * 4 + 3] = aw;
    __syncthreads();
    if (tid < 128) {
        float v = 0.f;
#pragma unroll
        for (int q = 0; q < 8; ++q) v += part[q][tid];
        size_t xi = (size_t)b * KX + dc * 128 + tid;
        Xh_[xi] = bhi(v);
        Xl_[xi] = blo(v);
    }
}

// gates = X[32x2560] @ Wg^T[4096x2560] + bias (split-bf16, 3 chains), fused LSTM
// pointwise. grid 256 x 256thr: block = 16 cols; 4 waves = 4-way K-split (640 each);
// LDS reduce; epilogue writes c, h, and X h-part.
__global__ __launch_bounds__(256) void k_gates(
    const bf16* __restrict__ Xh_, const bf16* __restrict__ Xl_,
    const bf16* __restrict__ Wh_, const bf16* __restrict__ Wl_,
    const float* __restrict__ bias,
    float* __restrict__ c, float* __restrict__ h,
    bf16* __restrict__ XhO, bf16* __restrict__ XlO)
{
    __shared__ float pr[4][32][17];
    int jb = blockIdx.x * 16;
    int tid = threadIdx.x, wave = tid >> 6, lane = tid & 63;
    int kq = wave;                       // K-quarter
    int jcol = jb + (lane & 15);
    int kc = kq * 640 + (lane >> 4) * 8;
    const short* xhp = (const short*)Xh_ + kc;
    const short* xlp = (const short*)Xl_ + kc;
    const short* wrh = (const short*)Wh_ + (size_t)jcol * KX + kc;
    const short* wrl = (const short*)Wl_ + (size_t)jcol * KX + kc;
    size_t arow0 = (size_t)(lane & 15) * KX;
    size_t arow1 = (size_t)((lane & 15) + 16) * KX;
    f32x4 acc0 = {0, 0, 0, 0}, acc1 = {0, 0, 0, 0};
#pragma unroll 4
    for (int kk = 0; kk < 20; ++kk) {
        int ko = kk * 32;
        short8 a0h = *(const short8*)(xhp + arow0 + ko);
        short8 a1h = *(const short8*)(xhp + arow1 + ko);
        short8 a0l = *(const short8*)(xlp + arow0 + ko);
        short8 a1l = *(const short8*)(xlp + arow1 + ko);
        short8 bh = *(const short8*)(wrh + ko);
        short8 bl = *(const short8*)(wrl + ko);
        acc0 = MFMA(a0h, bh, acc0); acc1 = MFMA(a1h, bh, acc1);
        acc0 = MFMA(a0h, bl, acc0); acc1 = MFMA(a1h, bl, acc1);
        acc0 = MFMA(a0l, bh, acc0); acc1 = MFMA(a1l, bh, acc1);
    }
#pragma unroll
    for (int r = 0; r < 4; ++r) {
        pr[kq][(lane >> 4) * 4 + r][lane & 15]      = acc0[r];
        pr[kq][16 + (lane >> 4) * 4 + r][lane & 15] = acc1[r];
    }
    __syncthreads();
    // 16 cols = 4 d-values (j' = 4d+g); 32 b x 4 d = 128 threads do pointwise.
    if (tid < 128) {
        int bb = tid & 31, dd = tid >> 5;
        int cb = dd * 4;
        float gi = pr[0][bb][cb+0] + pr[1][bb][cb+0] + pr[2][bb][cb+0] + pr[3][bb][cb+0] + bias[jb+cb+0];
        float gf = pr[0][bb][cb+1] + pr[1][bb][cb+1] + pr[2][bb][cb+1] + pr[3][bb][cb+1] + bias[jb+cb+1];
        float gg = pr[0][bb][cb+2] + pr[1][bb][cb+2] + pr[2][bb][cb+2] + pr[3][bb][cb+2] + bias[jb+cb+2];
        float go = pr[0][bb][cb+3] + pr[1][bb][cb+3] + pr[2][bb][cb+3] + pr[3][bb][cb+3] + bias[jb+cb+3];
        int d = (jb >> 2) + dd;
        float cv = c[bb * 1024 + d];
        float cn = sigmoidf_(gf) * cv + sigmoidf_(gi) * tanhf(gg);
        float hn = sigmoidf_(go) * tanhf(cn);
        c[bb * 1024 + d] = cn;
        h[bb * 1024 + d] = hn;
        XhO[(size_t)bb * KX + 1024 + d] = bhi(hn);
        XlO[(size_t)bb * KX + 1024 + d] = blo(hn);
    }
}

// OUT[m][v] = P[m][:] . emb_w[v][:],  m = b*64+t. P split hi/lo (2 chains), emb single bf16.
// 1D grid 16000: m-tiles inner (consecutive blocks share the Eb slice -> L2/L3 reuse).
// Nontemporal stores keep the 262 MB output stream from evicting Eb/P.
__global__ __launch_bounds__(256) void k_out(const bf16* __restrict__ Ph,
                                             const bf16* __restrict__ Pl,
                                             const bf16* __restrict__ Eb,
                                             float* __restrict__ out) {
    int bid = blockIdx.x;
    int vb = (bid >> 5) * 64;
    int mb = (bid & 31) * 64;
    __shared__ __align__(16) short ph[64][264];
    __shared__ __align__(16) short pl[64][264];
    int tid = threadIdx.x, wave = tid >> 6, lane = tid & 63;
    int wr = (wave >> 1) * 32, wc = (wave & 1) * 32;
    f32x4 acc[2][2] = {{{0, 0, 0, 0}, {0, 0, 0, 0}}, {{0, 0, 0, 0}, {0, 0, 0, 0}}};
    const short* e0 = (const short*)Eb + (size_t)(vb + wc + (lane & 15)) * 512 + (lane >> 4) * 8;
    const short* e1 = e0 + 16 * 512;

    for (int q = 0; q < 2; ++q) {
        __syncthreads();
        for (int i = tid; i < 64 * 32; i += 256) {
            int r = i >> 5, cc = i & 31;
            ((short8*)&ph[r][0])[cc] = *(const short8*)((const short*)Ph + (size_t)(mb + r) * 512 + q * 256 + cc * 8);
            ((short8*)&pl[r][0])[cc] = *(const short8*)((const short*)Pl + (size_t)(mb + r) * 512 + q * 256 + cc * 8);
        }
        __syncthreads();
#pragma unroll
        for (int kk = 0; kk < 8; ++kk) {
            int kcol = kk * 32 + (lane >> 4) * 8;
            short8 a0h = *(const short8*)(&ph[wr + (lane & 15)][kcol]);
            short8 a1h = *(const short8*)(&ph[wr + 16 + (lane & 15)][kcol]);
            short8 a0l = *(const short8*)(&pl[wr + (lane & 15)][kcol]);
            short8 a1l = *(const short8*)(&pl[wr + 16 + (lane & 15)][kcol]);
            short8 b0 = *(const short8*)(e0 + q * 256 + kk * 32);
            short8 b1 = *(const short8*)(e1 + q * 256 + kk * 32);
            acc[0][0] = MFMA(a0h, b0, acc[0][0]);
            acc[0][1] = MFMA(a0h, b1, acc[0][1]);
            acc[1][0] = MFMA(a1h, b0, acc[1][0]);
            acc[1][1] = MFMA(a1h, b1, acc[1][1]);
            acc[0][0] = MFMA(a0l, b0, acc[0][0]);
            acc[0][1] = MFMA(a0l, b1, acc[0][1]);
            acc[1][0] = MFMA(a1l, b0, acc[1][0]);
            acc[1][1] = MFMA(a1l, b1, acc[1][1]);
        }
    }
#pragma unroll
    for (int f0 = 0; f0 < 2; ++f0)
#pragma unroll
        for (int f1 = 0; f1 < 2; ++f1)
#pragma unroll
            for (int r = 0; r < 4; ++r) {
                int mm = mb + wr + 16 * f0 + (lane >> 4) * 4 + r;
                int vv = vb + wc + 16 * f1 + (lane & 15);
                __builtin_nontemporal_store(acc[f0][f1][r], &out[(size_t)mm * V_ + vv]);
            }
}

// ---------------- launcher ----------------

extern "C" void kernel_launch(void* const* d_in, const int* in_sizes, int n_in,
                              void* d_out, int out_size, void* d_ws, size_t ws_size,
                              hipStream_t stream) {
    (void)in_sizes; (void)n_in; (void)out_size; (void)ws_size;
    const float* enc    = (const float*)d_in[0];
    const float* mask   = (const float*)d_in[1];
    const int*   label  = (const int*)d_in[2];
    const float* emb_w  = (const float*)d_in[3];
    const float* W_ih   = (const float*)d_in[4];
    const float* b_ih   = (const float*)d_in[5];
    const float* W_hh   = (const float*)d_in[6];
    const float* b_hh   = (const float*)d_in[7];
    const float* proj_W = (const float*)d_in[8];
    const float* proj_b = (const float*)d_in[9];
    const float* emb0   = (const float*)d_in[10];
    const float* h0     = (const float*)d_in[11];
    const float* c0     = (const float*)d_in[12];
    float* out = (float*)d_out;

    char* w = (char*)d_ws;
    size_t o = 0;
    bf16* Wgh  = (bf16*)(w + o); o += (size_t)4096 * KX * 2;     // 21.0 MB
    bf16* Wgl  = (bf16*)(w + o); o += (size_t)4096 * KX * 2;     // 21.0 MB
    bf16* PWh  = (bf16*)(w + o); o += (size_t)512 * KP * 2;      // 2.1 MB
    bf16* PWl  = (bf16*)(w + o); o += (size_t)512 * KP * 2;      // 2.1 MB
    bf16* Eb   = (bf16*)(w + o); o += (size_t)V_ * 512 * 2;      // 32.8 MB
    float* bias= (float*)(w + o); o += 4096 * 4;
    bf16* Xh   = (bf16*)(w + o); o += (size_t)32 * KX * 2;
    bf16* Xl   = (bf16*)(w + o); o += (size_t)32 * KX * 2;
    bf16* Ph   = (bf16*)(w + o); o += (size_t)2048 * 512 * 2;    // 2.1 MB
    bf16* Pl   = (bf16*)(w + o); o += (size_t)2048 * 512 * 2;    // 2.1 MB
    float* hb  = (float*)(w + o); o += (size_t)32 * 1024 * 4;
    float* cb  = (float*)(w + o); o += (size_t)32 * 1024 * 4;
    float* sc  = (float*)(w + o); o += (size_t)32 * 512 * 4;
    // total ~84 MB

    k_build_wg<<<4096, 256, 0, stream>>>(W_ih, W_hh, b_ih, b_hh, Wgh, Wgl, bias);
    k_cvt_split<<<1024, 256, 0, stream>>>(proj_W, PWh, PWl, (long)512 * KP);
    k_cvt<<<8192, 256, 0, stream>>>(emb_w, Eb, (long)V_ * 512);
    k_init<<<32, 256, 0, stream>>>(h0, c0, emb0, hb, cb, Xh, Xl);

    for (int t = 0; t <= T_; ++t) {
        k_ps<<<544, 256, 0, stream>>>(enc, mask, hb, sc, Xh, Xl, PWh, PWl, proj_b,
                                      emb_w, label, Ph, Pl, t);
        if (t < T_) {
            k_ctx  <<<dim3(32, 8), 256, 0, stream>>>(enc, sc, Xh, Xl);
            k_gates<<<256, 256, 0, stream>>>(Xh, Xl, Wgh, Wgl, bias, cb, hb, Xh, Xl);
        }
    }
    k_out<<<16000, 256, 0, stream>>>(Ph, Pl, Eb, out);
}